// Round 10
// baseline (136.071 us; speedup 1.0000x reference)
//
#include <hip/hip_runtime.h>

#define NN 50000
#define EE 600000
#define CC 128
#define HH 8
#define ESTRIDE 150000   // EE/4: edges per scatter pass
#define GB 782           // gemm blocks = ceil(NN/64)
#define EPB 768          // edges per gemm block for fused hist (782*768 >= EE)
#define NBN 196          // ceil(NN/256)
#define LOG2E 1.4426950408889634f

typedef unsigned int u32;
typedef unsigned short u16;
typedef __attribute__((ext_vector_type(8))) short short8;
typedef __attribute__((ext_vector_type(4))) float f32x4;

__device__ __forceinline__ float b2f(u32 u) { return __uint_as_float(u << 16); }
__device__ __forceinline__ u16 f2b(float f) {
  u32 x = __float_as_uint(f);
  return (u16)((x + 0x7fffu + ((x >> 16) & 1u)) >> 16);
}
// packed f32x2 -> bf16x2 (RNE), S0 in low 16 bits
__device__ __forceinline__ u32 cvtpk(float lo, float hi) {
  u32 r;
  asm volatile("v_cvt_pk_bf16_f32 %0, %1, %2" : "=v"(r) : "v"(lo), "v"(hi));
  return r;
}

// workspace layout in 4-byte words
enum : int {
  OFF_FLAG = 0,
  OFF_CNT  = 64,
  OFF_OFFS = OFF_CNT + NN,
  OFF_CUR  = OFF_OFFS + NN + 64,
  OFF_BSUM = OFF_CUR + NN,          // 256 words
  OFF_WB   = OFF_BSUM + 256,        // 8192 words: bf16 W[128][128]
  OFF_SL   = OFF_WB + 8192,
  OFF_SR   = OFF_SL + NN * HH,
  OFF_SSRC = OFF_SR + NN * HH,      // u16 ssrc: EE/2 words
  OFF_EMB  = OFF_SSRC + EE / 2 + 64,
  WS_WORDS = OFF_EMB + NN * 64
};

// ---- prep: zero cnt, convert W->bf16, sniff edge dtype --------------------
__global__ __launch_bounds__(256) void k_prep(const int* __restrict__ ei, const float* __restrict__ W,
                                              int* __restrict__ flag, int* __restrict__ cnt,
                                              u32* __restrict__ Wb) {
  int i = blockIdx.x * 256 + threadIdx.x;
  if (i < NN) cnt[i] = 0;
  if (i < CC * CC / 2) {
    float2 v = ((const float2*)W)[i];
    Wb[i] = (u32)f2b(v.x) | ((u32)f2b(v.y) << 16);
  }
  if (blockIdx.x == 0) {
    __shared__ int any;
    if (threadIdx.x == 0) any = 0;
    __syncthreads();
    int nz = 0;
    for (int k = threadIdx.x; k < 1024; k += 256) nz |= (ei[2 * k + 1] != 0) ? 1 : 0;
    if (nz) any = 1;  // benign race
    __syncthreads();
    if (threadIdx.x == 0) flag[0] = any;  // 1 => int32 layout, 0 => int64 layout
  }
}

// ---- MFMA bf16 GEMM, BM=64, X global->register, W-only LDS ----------------
__device__ __forceinline__ int swz(int row, int byte_in_row) {
  return ((row * 256 + byte_in_row) ^ ((row & 7) << 4));
}

__global__ __launch_bounds__(256) void k_gemm(const float* __restrict__ X,
                                              const u32* __restrict__ Wb,
                                              const float* __restrict__ al,
                                              const float* __restrict__ ar,
                                              const int* __restrict__ ei,
                                              const int* __restrict__ flag,
                                              int* __restrict__ cnt,
                                              u32* __restrict__ emb,
                                              float* __restrict__ sl, float* __restrict__ sr) {
  __shared__ unsigned char lds[32768];
  const int tid = threadIdx.x;
  const int n0 = blockIdx.x * 64;
  const int lane = tid & 63;
  const int w = tid >> 6;
  const int cwh16 = lane & 15, kg = lane >> 4;

  // X A-fragment loads, direct to registers (8 x 16B in flight per lane)
  const int myrow = n0 + w * 16 + cwh16;
  float4 xa[8];
  {
    const float4* X4 = (const float4*)X;
    const bool ok = myrow < NN;
    const int base = myrow * 32 + kg * 2;   // float4 index; k-cols kk*32+kg*8..+7
#pragma unroll
    for (int kk = 0; kk < 4; ++kk) {
      xa[2 * kk]     = ok ? X4[base + kk * 8]     : make_float4(0.f, 0.f, 0.f, 0.f);
      xa[2 * kk + 1] = ok ? X4[base + kk * 8 + 1] : make_float4(0.f, 0.f, 0.f, 0.f);
    }
  }

  // fused histogram: this block's edge slice (latency hides under X/W loads)
  {
    const int f = flag[0];
    const int ebase = blockIdx.x * EPB;
    const int eend = (ebase + EPB < EE) ? ebase + EPB : EE;
    for (int e = ebase + tid; e < eend; e += 256) {
      int t = f ? ei[EE + e] : ((const int2*)ei)[EE + e].x;
      atomicAdd(&cnt[t], 1);
    }
  }

  // stage W (already bf16): 2048 x 16B pure copies, swizzled
#pragma unroll
  for (int i = 0; i < 8; ++i) {
    int idx = tid + i * 256;
    int r = idx >> 4, c16 = idx & 15;
    uint4 v = ((const uint4*)Wb)[idx];
    *(uint4*)&lds[swz(r, c16 * 16)] = v;
  }
  __syncthreads();

  f32x4 acc[8];
#pragma unroll
  for (int nt = 0; nt < 8; ++nt) acc[nt] = (f32x4){0.f, 0.f, 0.f, 0.f};

  union { u32 u[4]; short8 s8; } pa;
#pragma unroll
  for (int kk = 0; kk < 4; ++kk) {
    pa.u[0] = cvtpk(xa[2 * kk].x, xa[2 * kk].y);
    pa.u[1] = cvtpk(xa[2 * kk].z, xa[2 * kk].w);
    pa.u[2] = cvtpk(xa[2 * kk + 1].x, xa[2 * kk + 1].y);
    pa.u[3] = cvtpk(xa[2 * kk + 1].z, xa[2 * kk + 1].w);
    const short8 a = pa.s8;
    const int kb = kk * 64 + kg * 16;
#pragma unroll
    for (int nt = 0; nt < 8; ++nt) {
      short8 b = *(const short8*)&lds[swz(nt * 16 + cwh16, kb)];
      acc[nt] = __builtin_amdgcn_mfma_f32_16x16x32_bf16(a, b, acc[nt], 0, 0, 0);
    }
  }

  // store accumulators to LDS (bf16, swizzled, region reuses W's first 16 KB)
  __syncthreads();   // all waves done reading W
#pragma unroll
  for (int nt = 0; nt < 8; ++nt) {
    const int col = nt * 16 + cwh16;
#pragma unroll
    for (int reg = 0; reg < 4; ++reg) {
      const int r = w * 16 + kg * 4 + reg;
      *(u16*)&lds[swz(r, col * 2)] = f2b(acc[nt][reg]);
    }
  }
  __syncthreads();

  // fused scores from LDS emb tile (pre-scaled by log2(e) for exp2 in k_agg)
  {
    const int r = tid >> 2, hp = tid & 3;
    const int n = n0 + r;
    if (n < NN) {
      float sAl = 0.f, sAr = 0.f, sBl = 0.f, sBr = 0.f;
#pragma unroll
      for (int j = 0; j < 2; ++j) {      // head 2hp, cwh j*8..j*8+7
        uint4 q = *(const uint4*)&lds[swz(r, hp * 64 + j * 16)];
        u32 qq[4] = {q.x, q.y, q.z, q.w};
        const int h = 2 * hp;
#pragma unroll
        for (int u = 0; u < 4; ++u) {
          int cwh = j * 8 + 2 * u;
          float lo = b2f(qq[u] & 0xffffu), hi = b2f(qq[u] >> 16);
          sAl = fmaf(lo, al[cwh * 8 + h], sAl);       sAr = fmaf(lo, ar[cwh * 8 + h], sAr);
          sAl = fmaf(hi, al[(cwh + 1) * 8 + h], sAl); sAr = fmaf(hi, ar[(cwh + 1) * 8 + h], sAr);
        }
      }
#pragma unroll
      for (int j = 0; j < 2; ++j) {      // head 2hp+1
        uint4 q = *(const uint4*)&lds[swz(r, hp * 64 + 32 + j * 16)];
        u32 qq[4] = {q.x, q.y, q.z, q.w};
        const int h = 2 * hp + 1;
#pragma unroll
        for (int u = 0; u < 4; ++u) {
          int cwh = j * 8 + 2 * u;
          float lo = b2f(qq[u] & 0xffffu), hi = b2f(qq[u] >> 16);
          sBl = fmaf(lo, al[cwh * 8 + h], sBl);       sBr = fmaf(lo, ar[cwh * 8 + h], sBr);
          sBl = fmaf(hi, al[(cwh + 1) * 8 + h], sBl); sBr = fmaf(hi, ar[(cwh + 1) * 8 + h], sBr);
        }
      }
      ((float2*)&sl[n * HH])[hp] = make_float2(sAl * LOG2E, sBl * LOG2E);
      ((float2*)&sr[n * HH])[hp] = make_float2(sAr * LOG2E, sBr * LOG2E);
    }
  }

  // emb global write: 1024 x 16B coalesced
#pragma unroll
  for (int i = 0; i < 4; ++i) {
    int idx = tid + i * 256;
    int r = idx >> 4, c16 = idx & 15;
    int n = n0 + r;
    if (n < NN) {
      uint4 v = *(const uint4*)&lds[swz(r, c16 * 16)];
      *((uint4*)(emb + n * 64 + c16 * 4)) = v;
    }
  }
}

// ---- CSR scan chain (2 kernels) -------------------------------------------
__global__ __launch_bounds__(256) void k_scanA(const int* __restrict__ cnt, int* __restrict__ offs,
                                               int* __restrict__ bsum) {
  __shared__ int tmp[256];
  const int t = threadIdx.x;
  const int i = blockIdx.x * 256 + t;
  int v = (i < NN) ? cnt[i] : 0;
  tmp[t] = v;
  __syncthreads();
#pragma unroll
  for (int d = 1; d < 256; d <<= 1) {
    int x = (t >= d) ? tmp[t - d] : 0;
    __syncthreads();
    tmp[t] += x;
    __syncthreads();
  }
  if (i < NN) offs[i] = tmp[t] - v;      // block-local exclusive
  if (t == 255) bsum[blockIdx.x] = tmp[255];
}

// every block redundantly scans the 196 block sums, then finalizes its slice
__global__ __launch_bounds__(256) void k_scanBC(const int* __restrict__ bsum, int* __restrict__ offs,
                                                int* __restrict__ cur) {
  __shared__ int tmp[256];
  const int t = threadIdx.x;
  int v = (t < NBN) ? bsum[t] : 0;
  tmp[t] = v;
  __syncthreads();
#pragma unroll
  for (int d = 1; d < 256; d <<= 1) {
    int x = (t >= d) ? tmp[t - d] : 0;
    __syncthreads();
    tmp[t] += x;
    __syncthreads();
  }
  const int base = (blockIdx.x == 0) ? 0 : tmp[blockIdx.x - 1];  // inclusive prefix
  const int i = blockIdx.x * 256 + t;
  if (i < NN) {
    int o = offs[i] + base;
    offs[i] = o;
    cur[i] = o;
  }
  if (i == 0) offs[NN] = EE;
}

__global__ __launch_bounds__(256) void k_scatter(const int* __restrict__ ei, const int* __restrict__ flag,
                                                 int* __restrict__ cur, u16* __restrict__ ssrc) {
  const int tid = blockIdx.x * 256 + threadIdx.x;
  if (tid >= ESTRIDE) return;
  const int f = flag[0];
  int s[4], t[4];
  if (f) {
#pragma unroll
    for (int k = 0; k < 4; ++k) {
      s[k] = ei[tid + k * ESTRIDE];
      t[k] = ei[EE + tid + k * ESTRIDE];
    }
  } else {
#pragma unroll
    for (int k = 0; k < 4; ++k) {
      s[k] = ((const int2*)ei)[tid + k * ESTRIDE].x;
      t[k] = ((const int2*)ei)[EE + tid + k * ESTRIDE].x;
    }
  }
  int pos[4];
#pragma unroll
  for (int k = 0; k < 4; ++k) pos[k] = atomicAdd(&cur[t[k]], 1);
#pragma unroll
  for (int k = 0; k < 4; ++k) ssrc[pos[k]] = (u16)s[k];
}

// ---- aggregation: wave-cooperative weights, 8 edges/chunk -----------------
// lane l: head h2 = l>>3 owns channels (2l, 2l+1); slot p = l&7.
// Chunk of 8 edges: lane computes weight for (edge e+p, head h2) — all 64
// lanes distinct work. Broadcast w/s via shfl for the fmaf accumulation.
__global__ __launch_bounds__(256) void k_agg(const u32* __restrict__ emb,
                                             const float* __restrict__ sl, const float* __restrict__ sr,
                                             const int* __restrict__ offs, const u16* __restrict__ ssrc,
                                             const float* __restrict__ bias, float* __restrict__ out) {
  const int t = (blockIdx.x * 256 + threadIdx.x) >> 6;
  const int lane = threadIdx.x & 63;
  if (t >= NN) return;
  const int e0 = offs[t], e1 = offs[t + 1];
  const int h2 = lane >> 3;
  const int p = lane & 7;
  const int gbase = lane & 56;          // head-group base lane
  const float sr2 = sr[t * HH + h2];
  float ax = 0.f, ay = 0.f, denl = 0.f;
  for (int e = e0; e < e1; e += 8) {
    const int ide = e + p;
    const bool ok = ide < e1;
    const int s_local = (int)ssrc[ok ? ide : e0];
    float vv = sl[s_local * HH + h2] + sr2;
    vv = fmaxf(vv, 0.2f * vv);          // LeakyReLU(0.2), scores pre-scaled by log2e
    const float wloc = ok ? exp2f(vv) : 0.f;
    denl += wloc;
#pragma unroll
    for (int j = 0; j < 8; ++j) {
      if (e + j >= e1) break;           // wave-uniform scalar branch
      const float wj = __shfl(wloc, gbase | j);
      const int sj = __shfl(s_local, j);
      const u32 pj = emb[sj * 64 + lane];
      ax = fmaf(wj, b2f(pj & 0xffffu), ax);
      ay = fmaf(wj, b2f(pj >> 16), ay);
    }
  }
  // denominator: reduce over the 8 slots within this head group
  denl += __shfl_xor(denl, 1);
  denl += __shfl_xor(denl, 2);
  denl += __shfl_xor(denl, 4);
  const float inv = 1.f / (denl + 1e-16f);
  float2 bv = ((const float2*)bias)[lane];
  ((float2*)out)[t * 64 + lane] = make_float2(fmaf(ax, inv, bv.x), fmaf(ay, inv, bv.y));
}

extern "C" void kernel_launch(void* const* d_in, const int* in_sizes, int n_in,
                              void* d_out, int out_size, void* d_ws, size_t ws_size,
                              hipStream_t stream) {
  const float* X  = (const float*)d_in[0];
  const int*   EI = (const int*)d_in[1];
  const float* W  = (const float*)d_in[2];
  const float* AL = (const float*)d_in[3];
  const float* AR = (const float*)d_in[4];
  const float* B  = (const float*)d_in[5];
  float* out = (float*)d_out;
  u32* ws = (u32*)d_ws;

  int*   flag = (int*)(ws + OFF_FLAG);
  int*   cnt  = (int*)(ws + OFF_CNT);
  int*   offs = (int*)(ws + OFF_OFFS);
  int*   cur  = (int*)(ws + OFF_CUR);
  int*   bsum = (int*)(ws + OFF_BSUM);
  u32*   Wb   = (u32*)(ws + OFF_WB);
  float* sl   = (float*)(ws + OFF_SL);
  float* sr   = (float*)(ws + OFF_SR);
  u16*   ssrc = (u16*)(ws + OFF_SSRC);
  u32*   emb  = (u32*)(ws + OFF_EMB);

  const int nbEs = (ESTRIDE + 255) / 256;  // 586

  k_prep<<<NBN, 256, 0, stream>>>(EI, W, flag, cnt, Wb);
  k_gemm<<<GB, 256, 0, stream>>>(X, Wb, AL, AR, EI, flag, cnt, emb, sl, sr);
  k_scanA<<<NBN, 256, 0, stream>>>(cnt, offs, bsum);
  k_scanBC<<<NBN, 256, 0, stream>>>(bsum, offs, cur);
  k_scatter<<<nbEs, 256, 0, stream>>>(EI, flag, cur, ssrc);
  k_agg<<<(NN * 64 + 255) / 256, 256, 0, stream>>>(emb, sl, sr, offs, ssrc, B, out);
}

// Round 11
// 134.373 us; speedup vs baseline: 1.0126x; 1.0126x over previous
//
#include <hip/hip_runtime.h>

#define NN 50000
#define EE 600000
#define CC 128
#define HH 8
#define ESTRIDE 150000   // EE/4: edges per scatter pass
#define GB 782           // gemm blocks = ceil(NN/64)
#define EPB 768          // edges per gemm block for fused hist (782*768 >= EE)
#define NBN 196          // ceil(NN/256)
#define LOG2E 1.4426950408889634f

typedef unsigned int u32;
typedef unsigned short u16;
typedef __attribute__((ext_vector_type(8))) short short8;
typedef __attribute__((ext_vector_type(4))) float f32x4;

__device__ __forceinline__ float b2f(u32 u) { return __uint_as_float(u << 16); }
__device__ __forceinline__ u16 f2b(float f) {
  u32 x = __float_as_uint(f);
  return (u16)((x + 0x7fffu + ((x >> 16) & 1u)) >> 16);
}
// packed f32x2 -> bf16x2 (RNE), S0 in low 16 bits
__device__ __forceinline__ u32 cvtpk(float lo, float hi) {
  u32 r;
  asm volatile("v_cvt_pk_bf16_f32 %0, %1, %2" : "=v"(r) : "v"(lo), "v"(hi));
  return r;
}

// workspace layout in 4-byte words
enum : int {
  OFF_FLAG = 0,
  OFF_CNT  = 64,
  OFF_OFFS = OFF_CNT + NN,
  OFF_CUR  = OFF_OFFS + NN + 64,
  OFF_BSUM = OFF_CUR + NN,          // 256 words
  OFF_WB   = OFF_BSUM + 256,        // 8192 words: bf16 W[128][128]
  OFF_SL   = OFF_WB + 8192,
  OFF_SR   = OFF_SL + NN * HH,
  OFF_SSRC = OFF_SR + NN * HH,      // u16 ssrc: EE/2 words
  OFF_EMB  = OFF_SSRC + EE / 2 + 64,
  OFF_WEXP = OFF_EMB + NN * 64,     // f32 per-(edge,head) weights: EE*8 words
  WS_WORDS = OFF_WEXP + EE * HH
};

// ---- prep: zero cnt, convert W->bf16, sniff edge dtype --------------------
__global__ __launch_bounds__(256) void k_prep(const int* __restrict__ ei, const float* __restrict__ W,
                                              int* __restrict__ flag, int* __restrict__ cnt,
                                              u32* __restrict__ Wb) {
  int i = blockIdx.x * 256 + threadIdx.x;
  if (i < NN) cnt[i] = 0;
  if (i < CC * CC / 2) {
    float2 v = ((const float2*)W)[i];
    Wb[i] = (u32)f2b(v.x) | ((u32)f2b(v.y) << 16);
  }
  if (blockIdx.x == 0) {
    __shared__ int any;
    if (threadIdx.x == 0) any = 0;
    __syncthreads();
    int nz = 0;
    for (int k = threadIdx.x; k < 1024; k += 256) nz |= (ei[2 * k + 1] != 0) ? 1 : 0;
    if (nz) any = 1;  // benign race
    __syncthreads();
    if (threadIdx.x == 0) flag[0] = any;  // 1 => int32 layout, 0 => int64 layout
  }
}

// ---- MFMA bf16 GEMM, BM=64, X global->register, W-only LDS ----------------
__device__ __forceinline__ int swz(int row, int byte_in_row) {
  return ((row * 256 + byte_in_row) ^ ((row & 7) << 4));
}

__global__ __launch_bounds__(256) void k_gemm(const float* __restrict__ X,
                                              const u32* __restrict__ Wb,
                                              const float* __restrict__ al,
                                              const float* __restrict__ ar,
                                              const int* __restrict__ ei,
                                              const int* __restrict__ flag,
                                              int* __restrict__ cnt,
                                              u32* __restrict__ emb,
                                              float* __restrict__ sl, float* __restrict__ sr) {
  __shared__ unsigned char lds[32768];
  const int tid = threadIdx.x;
  const int n0 = blockIdx.x * 64;
  const int lane = tid & 63;
  const int w = tid >> 6;
  const int cwh16 = lane & 15, kg = lane >> 4;

  // X A-fragment loads, direct to registers (8 x 16B in flight per lane)
  const int myrow = n0 + w * 16 + cwh16;
  float4 xa[8];
  {
    const float4* X4 = (const float4*)X;
    const bool ok = myrow < NN;
    const int base = myrow * 32 + kg * 2;   // float4 index; k-cols kk*32+kg*8..+7
#pragma unroll
    for (int kk = 0; kk < 4; ++kk) {
      xa[2 * kk]     = ok ? X4[base + kk * 8]     : make_float4(0.f, 0.f, 0.f, 0.f);
      xa[2 * kk + 1] = ok ? X4[base + kk * 8 + 1] : make_float4(0.f, 0.f, 0.f, 0.f);
    }
  }

  // fused histogram: this block's edge slice (latency hides under X/W loads)
  {
    const int f = flag[0];
    const int ebase = blockIdx.x * EPB;
    const int eend = (ebase + EPB < EE) ? ebase + EPB : EE;
    for (int e = ebase + tid; e < eend; e += 256) {
      int t = f ? ei[EE + e] : ((const int2*)ei)[EE + e].x;
      atomicAdd(&cnt[t], 1);
    }
  }

  // stage W (already bf16): 2048 x 16B pure copies, swizzled
#pragma unroll
  for (int i = 0; i < 8; ++i) {
    int idx = tid + i * 256;
    int r = idx >> 4, c16 = idx & 15;
    uint4 v = ((const uint4*)Wb)[idx];
    *(uint4*)&lds[swz(r, c16 * 16)] = v;
  }
  __syncthreads();

  f32x4 acc[8];
#pragma unroll
  for (int nt = 0; nt < 8; ++nt) acc[nt] = (f32x4){0.f, 0.f, 0.f, 0.f};

  union { u32 u[4]; short8 s8; } pa;
#pragma unroll
  for (int kk = 0; kk < 4; ++kk) {
    pa.u[0] = cvtpk(xa[2 * kk].x, xa[2 * kk].y);
    pa.u[1] = cvtpk(xa[2 * kk].z, xa[2 * kk].w);
    pa.u[2] = cvtpk(xa[2 * kk + 1].x, xa[2 * kk + 1].y);
    pa.u[3] = cvtpk(xa[2 * kk + 1].z, xa[2 * kk + 1].w);
    const short8 a = pa.s8;
    const int kb = kk * 64 + kg * 16;
#pragma unroll
    for (int nt = 0; nt < 8; ++nt) {
      short8 b = *(const short8*)&lds[swz(nt * 16 + cwh16, kb)];
      acc[nt] = __builtin_amdgcn_mfma_f32_16x16x32_bf16(a, b, acc[nt], 0, 0, 0);
    }
  }

  // store accumulators to LDS (bf16, swizzled, region reuses W's first 16 KB)
  __syncthreads();   // all waves done reading W
#pragma unroll
  for (int nt = 0; nt < 8; ++nt) {
    const int col = nt * 16 + cwh16;
#pragma unroll
    for (int reg = 0; reg < 4; ++reg) {
      const int r = w * 16 + kg * 4 + reg;
      *(u16*)&lds[swz(r, col * 2)] = f2b(acc[nt][reg]);
    }
  }
  __syncthreads();

  // fused scores from LDS emb tile (pre-scaled by log2(e) for exp2 in scatter)
  {
    const int r = tid >> 2, hp = tid & 3;
    const int n = n0 + r;
    if (n < NN) {
      float sAl = 0.f, sAr = 0.f, sBl = 0.f, sBr = 0.f;
#pragma unroll
      for (int j = 0; j < 2; ++j) {      // head 2hp, cwh j*8..j*8+7
        uint4 q = *(const uint4*)&lds[swz(r, hp * 64 + j * 16)];
        u32 qq[4] = {q.x, q.y, q.z, q.w};
        const int h = 2 * hp;
#pragma unroll
        for (int u = 0; u < 4; ++u) {
          int cwh = j * 8 + 2 * u;
          float lo = b2f(qq[u] & 0xffffu), hi = b2f(qq[u] >> 16);
          sAl = fmaf(lo, al[cwh * 8 + h], sAl);       sAr = fmaf(lo, ar[cwh * 8 + h], sAr);
          sAl = fmaf(hi, al[(cwh + 1) * 8 + h], sAl); sAr = fmaf(hi, ar[(cwh + 1) * 8 + h], sAr);
        }
      }
#pragma unroll
      for (int j = 0; j < 2; ++j) {      // head 2hp+1
        uint4 q = *(const uint4*)&lds[swz(r, hp * 64 + 32 + j * 16)];
        u32 qq[4] = {q.x, q.y, q.z, q.w};
        const int h = 2 * hp + 1;
#pragma unroll
        for (int u = 0; u < 4; ++u) {
          int cwh = j * 8 + 2 * u;
          float lo = b2f(qq[u] & 0xffffu), hi = b2f(qq[u] >> 16);
          sBl = fmaf(lo, al[cwh * 8 + h], sBl);       sBr = fmaf(lo, ar[cwh * 8 + h], sBr);
          sBl = fmaf(hi, al[(cwh + 1) * 8 + h], sBl); sBr = fmaf(hi, ar[(cwh + 1) * 8 + h], sBr);
        }
      }
      ((float2*)&sl[n * HH])[hp] = make_float2(sAl * LOG2E, sBl * LOG2E);
      ((float2*)&sr[n * HH])[hp] = make_float2(sAr * LOG2E, sBr * LOG2E);
    }
  }

  // emb global write: 1024 x 16B coalesced
#pragma unroll
  for (int i = 0; i < 4; ++i) {
    int idx = tid + i * 256;
    int r = idx >> 4, c16 = idx & 15;
    int n = n0 + r;
    if (n < NN) {
      uint4 v = *(const uint4*)&lds[swz(r, c16 * 16)];
      *((uint4*)(emb + n * 64 + c16 * 4)) = v;
    }
  }
}

// ---- CSR scan chain (2 kernels) -------------------------------------------
__global__ __launch_bounds__(256) void k_scanA(const int* __restrict__ cnt, int* __restrict__ offs,
                                               int* __restrict__ bsum) {
  __shared__ int tmp[256];
  const int t = threadIdx.x;
  const int i = blockIdx.x * 256 + t;
  int v = (i < NN) ? cnt[i] : 0;
  tmp[t] = v;
  __syncthreads();
#pragma unroll
  for (int d = 1; d < 256; d <<= 1) {
    int x = (t >= d) ? tmp[t - d] : 0;
    __syncthreads();
    tmp[t] += x;
    __syncthreads();
  }
  if (i < NN) offs[i] = tmp[t] - v;      // block-local exclusive
  if (t == 255) bsum[blockIdx.x] = tmp[255];
}

// every block redundantly scans the 196 block sums, then finalizes its slice
__global__ __launch_bounds__(256) void k_scanBC(const int* __restrict__ bsum, int* __restrict__ offs,
                                                int* __restrict__ cur) {
  __shared__ int tmp[256];
  const int t = threadIdx.x;
  int v = (t < NBN) ? bsum[t] : 0;
  tmp[t] = v;
  __syncthreads();
#pragma unroll
  for (int d = 1; d < 256; d <<= 1) {
    int x = (t >= d) ? tmp[t - d] : 0;
    __syncthreads();
    tmp[t] += x;
    __syncthreads();
  }
  const int base = (blockIdx.x == 0) ? 0 : tmp[blockIdx.x - 1];  // inclusive prefix
  const int i = blockIdx.x * 256 + t;
  if (i < NN) {
    int o = offs[i] + base;
    offs[i] = o;
    cur[i] = o;
  }
  if (i == 0) offs[NN] = EE;
}

// ---- scatter + fused per-(edge,head) weight computation -------------------
__global__ __launch_bounds__(256) void k_scatter(const int* __restrict__ ei, const int* __restrict__ flag,
                                                 const float* __restrict__ sl, const float* __restrict__ sr,
                                                 int* __restrict__ cur, u16* __restrict__ ssrc,
                                                 float* __restrict__ wexp) {
  const int tid = blockIdx.x * 256 + threadIdx.x;
  if (tid >= ESTRIDE) return;
  const int f = flag[0];
  int s[4], t[4];
  if (f) {
#pragma unroll
    for (int k = 0; k < 4; ++k) {
      s[k] = ei[tid + k * ESTRIDE];
      t[k] = ei[EE + tid + k * ESTRIDE];
    }
  } else {
#pragma unroll
    for (int k = 0; k < 4; ++k) {
      s[k] = ((const int2*)ei)[tid + k * ESTRIDE].x;
      t[k] = ((const int2*)ei)[EE + tid + k * ESTRIDE].x;
    }
  }
  int pos[4];
#pragma unroll
  for (int k = 0; k < 4; ++k) pos[k] = atomicAdd(&cur[t[k]], 1);
  // weights for all 8 heads, once per edge (overlaps atomic latency)
#pragma unroll
  for (int k = 0; k < 4; ++k) {
    float4 a0 = ((const float4*)sl)[s[k] * 2];
    float4 a1 = ((const float4*)sl)[s[k] * 2 + 1];
    float4 b0 = ((const float4*)sr)[t[k] * 2];
    float4 b1 = ((const float4*)sr)[t[k] * 2 + 1];
    float wv[8];
    float va[8] = {a0.x, a0.y, a0.z, a0.w, a1.x, a1.y, a1.z, a1.w};
    float vb[8] = {b0.x, b0.y, b0.z, b0.w, b1.x, b1.y, b1.z, b1.w};
#pragma unroll
    for (int h = 0; h < 8; ++h) {
      float vv = va[h] + vb[h];
      vv = fmaxf(vv, 0.2f * vv);          // LeakyReLU(0.2), pre-scaled by log2e
      wv[h] = exp2f(vv);
    }
    ((float4*)wexp)[pos[k] * 2]     = make_float4(wv[0], wv[1], wv[2], wv[3]);
    ((float4*)wexp)[pos[k] * 2 + 1] = make_float4(wv[4], wv[5], wv[6], wv[7]);
    ssrc[pos[k]] = (u16)s[k];
  }
}

// ---- aggregation: precomputed weights, predicated 16-wide -----------------
__global__ __launch_bounds__(256) void k_agg(const u32* __restrict__ emb,
                                             const float* __restrict__ wexp,
                                             const int* __restrict__ offs, const u16* __restrict__ ssrc,
                                             const float* __restrict__ bias, float* __restrict__ out) {
  const int t = (blockIdx.x * 256 + threadIdx.x) >> 6;
  const int lane = threadIdx.x & 63;
  if (t >= NN) return;
  const int e0 = offs[t], e1 = offs[t + 1];
  const int h2 = lane >> 3;
  float ax = 0.f, ay = 0.f, den = 0.f;
  for (int e = e0; e < e1; e += 16) {
    int idx[16];
#pragma unroll
    for (int k = 0; k < 16; ++k) idx[k] = (e + k < e1) ? e + k : e0;
    int s[16];
    float w[16];
    u32 p[16];
#pragma unroll
    for (int k = 0; k < 16; ++k) s[k] = (int)ssrc[idx[k]];
#pragma unroll
    for (int k = 0; k < 16; ++k) w[k] = wexp[idx[k] * HH + h2];
#pragma unroll
    for (int k = 0; k < 16; ++k) p[k] = emb[s[k] * 64 + lane];
#pragma unroll
    for (int k = 0; k < 16; ++k) {
      float wgt = (e + k < e1) ? w[k] : 0.f;
      den += wgt;
      ax = fmaf(wgt, b2f(p[k] & 0xffffu), ax);
      ay = fmaf(wgt, b2f(p[k] >> 16), ay);
    }
  }
  const float inv = 1.f / (den + 1e-16f);
  float2 bv = ((const float2*)bias)[lane];
  ((float2*)out)[t * 64 + lane] = make_float2(fmaf(ax, inv, bv.x), fmaf(ay, inv, bv.y));
}

extern "C" void kernel_launch(void* const* d_in, const int* in_sizes, int n_in,
                              void* d_out, int out_size, void* d_ws, size_t ws_size,
                              hipStream_t stream) {
  const float* X  = (const float*)d_in[0];
  const int*   EI = (const int*)d_in[1];
  const float* W  = (const float*)d_in[2];
  const float* AL = (const float*)d_in[3];
  const float* AR = (const float*)d_in[4];
  const float* B  = (const float*)d_in[5];
  float* out = (float*)d_out;
  u32* ws = (u32*)d_ws;

  int*   flag = (int*)(ws + OFF_FLAG);
  int*   cnt  = (int*)(ws + OFF_CNT);
  int*   offs = (int*)(ws + OFF_OFFS);
  int*   cur  = (int*)(ws + OFF_CUR);
  int*   bsum = (int*)(ws + OFF_BSUM);
  u32*   Wb   = (u32*)(ws + OFF_WB);
  float* sl   = (float*)(ws + OFF_SL);
  float* sr   = (float*)(ws + OFF_SR);
  u16*   ssrc = (u16*)(ws + OFF_SSRC);
  u32*   emb  = (u32*)(ws + OFF_EMB);
  float* wexp = (float*)(ws + OFF_WEXP);

  const int nbEs = (ESTRIDE + 255) / 256;  // 586

  k_prep<<<NBN, 256, 0, stream>>>(EI, W, flag, cnt, Wb);
  k_gemm<<<GB, 256, 0, stream>>>(X, Wb, AL, AR, EI, flag, cnt, emb, sl, sr);
  k_scanA<<<NBN, 256, 0, stream>>>(cnt, offs, bsum);
  k_scanBC<<<NBN, 256, 0, stream>>>(bsum, offs, cur);
  k_scatter<<<nbEs, 256, 0, stream>>>(EI, flag, sl, sr, cur, ssrc, wexp);
  k_agg<<<(NN * 64 + 255) / 256, 256, 0, stream>>>(emb, wexp, offs, ssrc, B, out);
}

// Round 12
// 121.239 us; speedup vs baseline: 1.1223x; 1.1083x over previous
//
#include <hip/hip_runtime.h>

#define NN 50000
#define EE 600000
#define CC 128
#define HH 8
#define ESTRIDE 150000   // EE/4: edges per scatter pass
#define GB 782           // gemm blocks = ceil(NN/64)
#define EPB 768          // edges per gemm block for fused hist (782*768 >= EE)
#define NBN 196          // ceil(NN/256)
#define LOG2E 1.4426950408889634f

typedef unsigned int u32;
typedef unsigned short u16;
typedef __attribute__((ext_vector_type(8))) short short8;
typedef __attribute__((ext_vector_type(4))) float f32x4;

__device__ __forceinline__ float b2f(u32 u) { return __uint_as_float(u << 16); }
__device__ __forceinline__ u16 f2b(float f) {
  u32 x = __float_as_uint(f);
  return (u16)((x + 0x7fffu + ((x >> 16) & 1u)) >> 16);
}
// packed f32x2 -> bf16x2 (RNE), S0 in low 16 bits
__device__ __forceinline__ u32 cvtpk(float lo, float hi) {
  u32 r;
  asm volatile("v_cvt_pk_bf16_f32 %0, %1, %2" : "=v"(r) : "v"(lo), "v"(hi));
  return r;
}

// workspace layout in 4-byte words
enum : int {
  OFF_FLAG = 0,
  OFF_CNT  = 64,
  OFF_OFFS = OFF_CNT + NN,
  OFF_CUR  = OFF_OFFS + NN + 64,
  OFF_BSUM = OFF_CUR + NN,          // 256 words
  OFF_WB   = OFF_BSUM + 256,        // 8192 words: bf16 W[128][128]
  OFF_SL   = OFF_WB + 8192,
  OFF_SR   = OFF_SL + NN * HH,
  OFF_SSRC = OFF_SR + NN * HH,      // u16 ssrc: EE/2 words
  OFF_EMB  = OFF_SSRC + EE / 2 + 64,
  WS_WORDS = OFF_EMB + NN * 64
};

// ---- prep: zero cnt, convert W->bf16, sniff edge dtype --------------------
__global__ __launch_bounds__(256) void k_prep(const int* __restrict__ ei, const float* __restrict__ W,
                                              int* __restrict__ flag, int* __restrict__ cnt,
                                              u32* __restrict__ Wb) {
  int i = blockIdx.x * 256 + threadIdx.x;
  if (i < NN) cnt[i] = 0;
  if (i < CC * CC / 2) {
    float2 v = ((const float2*)W)[i];
    Wb[i] = (u32)f2b(v.x) | ((u32)f2b(v.y) << 16);
  }
  if (blockIdx.x == 0) {
    __shared__ int any;
    if (threadIdx.x == 0) any = 0;
    __syncthreads();
    int nz = 0;
    for (int k = threadIdx.x; k < 1024; k += 256) nz |= (ei[2 * k + 1] != 0) ? 1 : 0;
    if (nz) any = 1;  // benign race
    __syncthreads();
    if (threadIdx.x == 0) flag[0] = any;  // 1 => int32 layout, 0 => int64 layout
  }
}

// ---- MFMA bf16 GEMM, BM=64, X global->register, W-only LDS ----------------
__device__ __forceinline__ int swz(int row, int byte_in_row) {
  return ((row * 256 + byte_in_row) ^ ((row & 7) << 4));
}

__global__ __launch_bounds__(256) void k_gemm(const float* __restrict__ X,
                                              const u32* __restrict__ Wb,
                                              const float* __restrict__ al,
                                              const float* __restrict__ ar,
                                              const int* __restrict__ ei,
                                              const int* __restrict__ flag,
                                              int* __restrict__ cnt,
                                              u32* __restrict__ emb,
                                              float* __restrict__ sl, float* __restrict__ sr) {
  __shared__ unsigned char lds[32768];
  const int tid = threadIdx.x;
  const int n0 = blockIdx.x * 64;
  const int lane = tid & 63;
  const int w = tid >> 6;
  const int cwh16 = lane & 15, kg = lane >> 4;

  // X A-fragment loads, direct to registers (8 x 16B in flight per lane)
  const int myrow = n0 + w * 16 + cwh16;
  float4 xa[8];
  {
    const float4* X4 = (const float4*)X;
    const bool ok = myrow < NN;
    const int base = myrow * 32 + kg * 2;   // float4 index; k-cols kk*32+kg*8..+7
#pragma unroll
    for (int kk = 0; kk < 4; ++kk) {
      xa[2 * kk]     = ok ? X4[base + kk * 8]     : make_float4(0.f, 0.f, 0.f, 0.f);
      xa[2 * kk + 1] = ok ? X4[base + kk * 8 + 1] : make_float4(0.f, 0.f, 0.f, 0.f);
    }
  }

  // fused histogram: this block's edge slice (latency hides under X/W loads)
  {
    const int f = flag[0];
    const int ebase = blockIdx.x * EPB;
    const int eend = (ebase + EPB < EE) ? ebase + EPB : EE;
    for (int e = ebase + tid; e < eend; e += 256) {
      int t = f ? ei[EE + e] : ((const int2*)ei)[EE + e].x;
      atomicAdd(&cnt[t], 1);
    }
  }

  // stage W (already bf16): 2048 x 16B pure copies, swizzled
#pragma unroll
  for (int i = 0; i < 8; ++i) {
    int idx = tid + i * 256;
    int r = idx >> 4, c16 = idx & 15;
    uint4 v = ((const uint4*)Wb)[idx];
    *(uint4*)&lds[swz(r, c16 * 16)] = v;
  }
  __syncthreads();

  f32x4 acc[8];
#pragma unroll
  for (int nt = 0; nt < 8; ++nt) acc[nt] = (f32x4){0.f, 0.f, 0.f, 0.f};

  union { u32 u[4]; short8 s8; } pa;
#pragma unroll
  for (int kk = 0; kk < 4; ++kk) {
    pa.u[0] = cvtpk(xa[2 * kk].x, xa[2 * kk].y);
    pa.u[1] = cvtpk(xa[2 * kk].z, xa[2 * kk].w);
    pa.u[2] = cvtpk(xa[2 * kk + 1].x, xa[2 * kk + 1].y);
    pa.u[3] = cvtpk(xa[2 * kk + 1].z, xa[2 * kk + 1].w);
    const short8 a = pa.s8;
    const int kb = kk * 64 + kg * 16;
#pragma unroll
    for (int nt = 0; nt < 8; ++nt) {
      short8 b = *(const short8*)&lds[swz(nt * 16 + cwh16, kb)];
      acc[nt] = __builtin_amdgcn_mfma_f32_16x16x32_bf16(a, b, acc[nt], 0, 0, 0);
    }
  }

  // store accumulators to LDS (bf16, swizzled, region reuses W's first 16 KB)
  __syncthreads();   // all waves done reading W
#pragma unroll
  for (int nt = 0; nt < 8; ++nt) {
    const int col = nt * 16 + cwh16;
#pragma unroll
    for (int reg = 0; reg < 4; ++reg) {
      const int r = w * 16 + kg * 4 + reg;
      *(u16*)&lds[swz(r, col * 2)] = f2b(acc[nt][reg]);
    }
  }
  __syncthreads();

  // fused scores from LDS emb tile (pre-scaled by log2(e) for exp2 in k_agg)
  {
    const int r = tid >> 2, hp = tid & 3;
    const int n = n0 + r;
    if (n < NN) {
      float sAl = 0.f, sAr = 0.f, sBl = 0.f, sBr = 0.f;
#pragma unroll
      for (int j = 0; j < 2; ++j) {      // head 2hp, cwh j*8..j*8+7
        uint4 q = *(const uint4*)&lds[swz(r, hp * 64 + j * 16)];
        u32 qq[4] = {q.x, q.y, q.z, q.w};
        const int h = 2 * hp;
#pragma unroll
        for (int u = 0; u < 4; ++u) {
          int cwh = j * 8 + 2 * u;
          float lo = b2f(qq[u] & 0xffffu), hi = b2f(qq[u] >> 16);
          sAl = fmaf(lo, al[cwh * 8 + h], sAl);       sAr = fmaf(lo, ar[cwh * 8 + h], sAr);
          sAl = fmaf(hi, al[(cwh + 1) * 8 + h], sAl); sAr = fmaf(hi, ar[(cwh + 1) * 8 + h], sAr);
        }
      }
#pragma unroll
      for (int j = 0; j < 2; ++j) {      // head 2hp+1
        uint4 q = *(const uint4*)&lds[swz(r, hp * 64 + 32 + j * 16)];
        u32 qq[4] = {q.x, q.y, q.z, q.w};
        const int h = 2 * hp + 1;
#pragma unroll
        for (int u = 0; u < 4; ++u) {
          int cwh = j * 8 + 2 * u;
          float lo = b2f(qq[u] & 0xffffu), hi = b2f(qq[u] >> 16);
          sBl = fmaf(lo, al[cwh * 8 + h], sBl);       sBr = fmaf(lo, ar[cwh * 8 + h], sBr);
          sBl = fmaf(hi, al[(cwh + 1) * 8 + h], sBl); sBr = fmaf(hi, ar[(cwh + 1) * 8 + h], sBr);
        }
      }
      ((float2*)&sl[n * HH])[hp] = make_float2(sAl * LOG2E, sBl * LOG2E);
      ((float2*)&sr[n * HH])[hp] = make_float2(sAr * LOG2E, sBr * LOG2E);
    }
  }

  // emb global write: 1024 x 16B coalesced
#pragma unroll
  for (int i = 0; i < 4; ++i) {
    int idx = tid + i * 256;
    int r = idx >> 4, c16 = idx & 15;
    int n = n0 + r;
    if (n < NN) {
      uint4 v = *(const uint4*)&lds[swz(r, c16 * 16)];
      *((uint4*)(emb + n * 64 + c16 * 4)) = v;
    }
  }
}

// ---- CSR scan chain (2 kernels) -------------------------------------------
__global__ __launch_bounds__(256) void k_scanA(const int* __restrict__ cnt, int* __restrict__ offs,
                                               int* __restrict__ bsum) {
  __shared__ int tmp[256];
  const int t = threadIdx.x;
  const int i = blockIdx.x * 256 + t;
  int v = (i < NN) ? cnt[i] : 0;
  tmp[t] = v;
  __syncthreads();
#pragma unroll
  for (int d = 1; d < 256; d <<= 1) {
    int x = (t >= d) ? tmp[t - d] : 0;
    __syncthreads();
    tmp[t] += x;
    __syncthreads();
  }
  if (i < NN) offs[i] = tmp[t] - v;      // block-local exclusive
  if (t == 255) bsum[blockIdx.x] = tmp[255];
}

// every block redundantly scans the 196 block sums, then finalizes its slice
__global__ __launch_bounds__(256) void k_scanBC(const int* __restrict__ bsum, int* __restrict__ offs,
                                                int* __restrict__ cur) {
  __shared__ int tmp[256];
  const int t = threadIdx.x;
  int v = (t < NBN) ? bsum[t] : 0;
  tmp[t] = v;
  __syncthreads();
#pragma unroll
  for (int d = 1; d < 256; d <<= 1) {
    int x = (t >= d) ? tmp[t - d] : 0;
    __syncthreads();
    tmp[t] += x;
    __syncthreads();
  }
  const int base = (blockIdx.x == 0) ? 0 : tmp[blockIdx.x - 1];  // inclusive prefix
  const int i = blockIdx.x * 256 + t;
  if (i < NN) {
    int o = offs[i] + base;
    offs[i] = o;
    cur[i] = o;
  }
  if (i == 0) offs[NN] = EE;
}

__global__ __launch_bounds__(256) void k_scatter(const int* __restrict__ ei, const int* __restrict__ flag,
                                                 int* __restrict__ cur, u16* __restrict__ ssrc) {
  const int tid = blockIdx.x * 256 + threadIdx.x;
  if (tid >= ESTRIDE) return;
  const int f = flag[0];
  int s[4], t[4];
  if (f) {
#pragma unroll
    for (int k = 0; k < 4; ++k) {
      s[k] = ei[tid + k * ESTRIDE];
      t[k] = ei[EE + tid + k * ESTRIDE];
    }
  } else {
#pragma unroll
    for (int k = 0; k < 4; ++k) {
      s[k] = ((const int2*)ei)[tid + k * ESTRIDE].x;
      t[k] = ((const int2*)ei)[EE + tid + k * ESTRIDE].x;
    }
  }
  int pos[4];
#pragma unroll
  for (int k = 0; k < 4; ++k) pos[k] = atomicAdd(&cur[t[k]], 1);
#pragma unroll
  for (int k = 0; k < 4; ++k) ssrc[pos[k]] = (u16)s[k];
}

// ---- aggregation: 4 channels/lane (uint2), 2 edges/wave-round -------------
// lane = 32*half + l5; lane covers channels 4*l5..4*l5+3 of head h2=l5>>2.
// half 0 processes even CSR slots, half 1 odd; one shfl_xor(32) merge at end.
__global__ __launch_bounds__(256) void k_agg(const u32* __restrict__ emb,
                                             const float* __restrict__ sl, const float* __restrict__ sr,
                                             const int* __restrict__ offs, const u16* __restrict__ ssrc,
                                             const float* __restrict__ bias, float* __restrict__ out) {
  const int t = (blockIdx.x * 256 + threadIdx.x) >> 6;
  const int lane = threadIdx.x & 63;
  if (t >= NN) return;
  const int e0 = offs[t], e1 = offs[t + 1];
  const int half = lane >> 5;
  const int l5 = lane & 31;
  const int h2 = l5 >> 2;
  const float sr2 = sr[t * HH + h2];
  const uint2* emb2 = (const uint2*)emb;
  float a0 = 0.f, a1 = 0.f, a2 = 0.f, a3 = 0.f, den = 0.f;
  for (int e = e0; e < e1; e += 16) {
    int idx[8];
    bool val[8];
#pragma unroll
    for (int k = 0; k < 8; ++k) {
      int j = e + half + 2 * k;
      val[k] = j < e1;
      idx[k] = val[k] ? j : e0;
    }
    int s[8];
#pragma unroll
    for (int k = 0; k < 8; ++k) s[k] = (int)ssrc[idx[k]];
    float v[8];
#pragma unroll
    for (int k = 0; k < 8; ++k) v[k] = sl[s[k] * HH + h2];
    uint2 p[8];
#pragma unroll
    for (int k = 0; k < 8; ++k) p[k] = emb2[s[k] * 32 + l5];
#pragma unroll
    for (int k = 0; k < 8; ++k) {
      float vv = v[k] + sr2;
      vv = fmaxf(vv, 0.2f * vv);          // LeakyReLU(0.2), scores pre-scaled by log2e
      float w = exp2f(vv);
      w = val[k] ? w : 0.f;
      den += w;
      a0 = fmaf(w, b2f(p[k].x & 0xffffu), a0);
      a1 = fmaf(w, b2f(p[k].x >> 16), a1);
      a2 = fmaf(w, b2f(p[k].y & 0xffffu), a2);
      a3 = fmaf(w, b2f(p[k].y >> 16), a3);
    }
  }
  a0 += __shfl_xor(a0, 32);
  a1 += __shfl_xor(a1, 32);
  a2 += __shfl_xor(a2, 32);
  a3 += __shfl_xor(a3, 32);
  den += __shfl_xor(den, 32);
  if (half == 0) {
    const float inv = 1.f / (den + 1e-16f);
    float4 bv = ((const float4*)bias)[l5];
    ((float4*)out)[t * 32 + l5] =
        make_float4(fmaf(a0, inv, bv.x), fmaf(a1, inv, bv.y),
                    fmaf(a2, inv, bv.z), fmaf(a3, inv, bv.w));
  }
}

extern "C" void kernel_launch(void* const* d_in, const int* in_sizes, int n_in,
                              void* d_out, int out_size, void* d_ws, size_t ws_size,
                              hipStream_t stream) {
  const float* X  = (const float*)d_in[0];
  const int*   EI = (const int*)d_in[1];
  const float* W  = (const float*)d_in[2];
  const float* AL = (const float*)d_in[3];
  const float* AR = (const float*)d_in[4];
  const float* B  = (const float*)d_in[5];
  float* out = (float*)d_out;
  u32* ws = (u32*)d_ws;

  int*   flag = (int*)(ws + OFF_FLAG);
  int*   cnt  = (int*)(ws + OFF_CNT);
  int*   offs = (int*)(ws + OFF_OFFS);
  int*   cur  = (int*)(ws + OFF_CUR);
  int*   bsum = (int*)(ws + OFF_BSUM);
  u32*   Wb   = (u32*)(ws + OFF_WB);
  float* sl   = (float*)(ws + OFF_SL);
  float* sr   = (float*)(ws + OFF_SR);
  u16*   ssrc = (u16*)(ws + OFF_SSRC);
  u32*   emb  = (u32*)(ws + OFF_EMB);

  const int nbEs = (ESTRIDE + 255) / 256;  // 586

  k_prep<<<NBN, 256, 0, stream>>>(EI, W, flag, cnt, Wb);
  k_gemm<<<GB, 256, 0, stream>>>(X, Wb, AL, AR, EI, flag, cnt, emb, sl, sr);
  k_scanA<<<NBN, 256, 0, stream>>>(cnt, offs, bsum);
  k_scanBC<<<NBN, 256, 0, stream>>>(bsum, offs, cur);
  k_scatter<<<nbEs, 256, 0, stream>>>(EI, flag, cur, ssrc);
  k_agg<<<(NN * 64 + 255) / 256, 256, 0, stream>>>(emb, sl, sr, offs, ssrc, B, out);
}